// Round 5
// baseline (522.929 us; speedup 1.0000x reference)
//
#include <hip/hip_runtime.h>
#include <hip/hip_bf16.h>

#define NN 100000
#define NE 1600000

// ---- edge dtype detection (proven int32 in r2≡r3, kept as cheap guard) ----

__global__ __launch_bounds__(256) void detect_kernel(const unsigned int* __restrict__ w,
                                                     int* __restrict__ is64) {
    __shared__ int nz;
    if (threadIdx.x == 0) nz = 0;
    __syncthreads();
    if (w[2 * threadIdx.x + 1] != 0) atomicAdd(&nz, 1);
    __syncthreads();
    if (threadIdx.x == 0) *is64 = (nz == 0) ? 1 : 0;
}

static __device__ __forceinline__ int edge_at(const void* ei, int is64, long long pos) {
    return is64 ? (int)((const long long*)ei)[pos] : ((const int*)ei)[pos];
}

// ---- preprocessing -------------------------------------------------------

__global__ __launch_bounds__(256) void deg_kernel(const void* __restrict__ ei,
                                                  const int* __restrict__ is64,
                                                  int* __restrict__ degi, int E) {
    int e = blockIdx.x * 256 + threadIdx.x;
    if (e < E) {
        int c = edge_at(ei, *is64, (long long)E + e);  // col = edge_index[1]
        atomicAdd(&degi[c], 1);
    }
}

__global__ __launch_bounds__(256) void dinv_kernel(const int* __restrict__ degi,
                                                   float* __restrict__ dinv, int N) {
    int i = blockIdx.x * 256 + threadIdx.x;
    if (i < N) dinv[i] = 1.0f / sqrtf((float)degi[i] + 1.0f);  // +1 self-loop
}

// segment start offsets: segment order irrelevant → block-scan + one atomic.
__global__ __launch_bounds__(256) void start_kernel(const int* __restrict__ degi,
                                                    int* __restrict__ start,
                                                    int* __restrict__ cursor,
                                                    int* __restrict__ counter, int N) {
    __shared__ int s[256];
    __shared__ int base;
    int tid = threadIdx.x;
    int i = blockIdx.x * 256 + tid;
    int v = (i < N) ? degi[i] : 0;
    int acc = v;
    s[tid] = v;
    __syncthreads();
    for (int off = 1; off < 256; off <<= 1) {
        int y = (tid >= off) ? s[tid - off] : 0;
        __syncthreads();
        acc += y;
        s[tid] = acc;
        __syncthreads();
    }
    if (tid == 255) base = atomicAdd(counter, acc);
    __syncthreads();
    int excl = base + acc - v;
    if (i < N) { start[i] = excl; cursor[i] = excl; }
}

__global__ __launch_bounds__(256) void scatter_kernel(const void* __restrict__ ei,
                                                      const int* __restrict__ is64,
                                                      int* __restrict__ cursor,
                                                      int* __restrict__ srow, int E) {
    int e = blockIdx.x * 256 + threadIdx.x;
    if (e < E) {
        int f = *is64;
        int r = edge_at(ei, f, e);                    // row (gather source)
        int c = edge_at(ei, f, (long long)E + e);     // col (scatter target)
        int p = atomicAdd(&cursor[c], 1);
        srow[p] = r;
    }
}

// ---- per-layer dense transform: t[n] = dinv[n] * (h[n] @ W) --------------
// h[n] = x[n] (layer 1)  or  dinv[n]*accin[n] + b_prev (folded finalize)

template <int DIN, int DOUT>
__global__ __launch_bounds__(256) void transform_kernel(
    const float* __restrict__ accin, const float* __restrict__ x,
    const float* __restrict__ W, const float* __restrict__ bprev,
    const float* __restrict__ dinv, float* __restrict__ t, int wcols, int N) {
    __shared__ float Wl[DIN * DOUT];
    __shared__ float bl[DIN];
    for (int i = threadIdx.x; i < DIN * DOUT; i += 256) {
        int k = i / DOUT, j = i - k * DOUT;
        Wl[i] = (j < wcols) ? W[k * wcols + j] : 0.0f;  // pad W5 cols to 4
    }
    if (bprev != nullptr)
        for (int i = threadIdx.x; i < DIN; i += 256) bl[i] = bprev[i];
    __syncthreads();

    int n = blockIdx.x * 256 + threadIdx.x;
    if (n >= N) return;
    float d = dinv[n];
    float h[DIN];
    if (x != nullptr) {
        const float4* x4 = (const float4*)x + n * (DIN / 4);
#pragma unroll
        for (int k4 = 0; k4 < DIN / 4; k4++) {
            float4 v = x4[k4];
            h[4 * k4 + 0] = v.x; h[4 * k4 + 1] = v.y;
            h[4 * k4 + 2] = v.z; h[4 * k4 + 3] = v.w;
        }
    } else {
        const float4* a4 = (const float4*)accin + n * (DIN / 4);
#pragma unroll
        for (int k4 = 0; k4 < DIN / 4; k4++) {
            float4 v = a4[k4];
            h[4 * k4 + 0] = d * v.x + bl[4 * k4 + 0];
            h[4 * k4 + 1] = d * v.y + bl[4 * k4 + 1];
            h[4 * k4 + 2] = d * v.z + bl[4 * k4 + 2];
            h[4 * k4 + 3] = d * v.w + bl[4 * k4 + 3];
        }
    }
    float4 o[DOUT / 4];
#pragma unroll
    for (int j = 0; j < DOUT / 4; j++) o[j] = make_float4(0.f, 0.f, 0.f, 0.f);
#pragma unroll
    for (int k = 0; k < DIN; k++) {
        float hk = h[k];
        const float4* w4 = (const float4*)&Wl[k * DOUT];
#pragma unroll
        for (int j = 0; j < DOUT / 4; j++) {
            float4 w = w4[j];
            o[j].x += hk * w.x; o[j].y += hk * w.y;
            o[j].z += hk * w.z; o[j].w += hk * w.w;
        }
    }
    float4* t4 = (float4*)t + n * (DOUT / 4);
#pragma unroll
    for (int j = 0; j < DOUT / 4; j++) {
        o[j].x *= d; o[j].y *= d; o[j].z *= d; o[j].w *= d;
        t4[j] = o[j];
    }
}

// ---- CSR aggregation: acc[c] = t[c] + sum over incoming edges of t[row] --
// NC = float4 chunks per node row (8 for dims 32, 1 for padded dim 4)

template <int NC>
__global__ __launch_bounds__(256) void aggregate_csr(
    const int* __restrict__ start, const int* __restrict__ degi,
    const int* __restrict__ srow, const float* __restrict__ t,
    float* __restrict__ acc, int N) {
    int tid = blockIdx.x * 256 + threadIdx.x;
    int c = tid / NC, j = tid - (tid / NC) * NC;
    if (c >= N) return;
    int s = start[c];
    int d = degi[c];
    const float4* tv = (const float4*)t;
    float4 a = tv[c * NC + j];  // self-loop term
    for (int i = 0; i < d; i++) {
        int r = srow[s + i];
        float4 v = tv[r * NC + j];
        a.x += v.x; a.y += v.y; a.z += v.z; a.w += v.w;
    }
    ((float4*)acc)[c * NC + j] = a;
}

// ---- final: out fp32 [N,3] — output follows the reference dtype (fp32) ---

__global__ __launch_bounds__(256) void finalize_kernel(
    const float* __restrict__ acc4, const float* __restrict__ b5,
    const float* __restrict__ dinv, float* __restrict__ out, int N) {
    int i = blockIdx.x * 256 + threadIdx.x;
    if (i >= N * 3) return;
    int n = i / 3, j = i - n * 3;
    out[i] = dinv[n] * acc4[n * 4 + j] + b5[j];
}

// ---- launch --------------------------------------------------------------

extern "C" void kernel_launch(void* const* d_in, const int* in_sizes, int n_in,
                              void* d_out, int out_size, void* d_ws, size_t ws_size,
                              hipStream_t stream) {
    const float* x  = (const float*)d_in[0];
    const void*  ei = d_in[1];  // int32 (detected; int64 path kept as guard)
    const float* W1 = (const float*)d_in[2];  const float* b1 = (const float*)d_in[3];
    const float* W2 = (const float*)d_in[4];  const float* b2 = (const float*)d_in[5];
    const float* W3 = (const float*)d_in[6];  const float* b3 = (const float*)d_in[7];
    const float* W4 = (const float*)d_in[8];  const float* b4 = (const float*)d_in[9];
    const float* W5 = (const float*)d_in[10]; const float* b5 = (const float*)d_in[11];
    float* out = (float*)d_out;

    char* p = (char*)d_ws;
    auto alloc = [&](size_t bytes) {
        char* r = p;
        p += (bytes + 255) & ~(size_t)255;
        return r;
    };
    int*   degi    = (int*)alloc(NN * 4);
    float* dinv    = (float*)alloc(NN * 4);
    int*   start   = (int*)alloc(NN * 4);
    int*   cursor  = (int*)alloc(NN * 4);
    int*   counter = (int*)alloc(256);
    int*   is64    = (int*)alloc(256);
    int*   srow    = (int*)alloc((size_t)NE * 4);
    float* A       = (float*)alloc((size_t)NN * 32 * 4);  // t, dims-32 layers
    float* B       = (float*)alloc((size_t)NN * 32 * 4);  // acc, dims-32 layers
    float* C       = (float*)alloc((size_t)NN * 4 * 4);   // t, layer 5 (3->4 pad)
    float* D       = (float*)alloc((size_t)NN * 4 * 4);   // acc, layer 5
    if ((size_t)(p - (char*)d_ws) > ws_size) return;      // canary: zero output

    hipMemsetAsync(degi, 0, NN * 4, stream);
    hipMemsetAsync(counter, 0, 4, stream);

    int gE = (NE + 255) / 256, gN = (NN + 255) / 256;
    detect_kernel<<<1, 256, 0, stream>>>((const unsigned int*)ei, is64);
    deg_kernel<<<gE, 256, 0, stream>>>(ei, is64, degi, NE);
    dinv_kernel<<<gN, 256, 0, stream>>>(degi, dinv, NN);
    start_kernel<<<gN, 256, 0, stream>>>(degi, start, cursor, counter, NN);
    scatter_kernel<<<gE, 256, 0, stream>>>(ei, is64, cursor, srow, NE);

    int gAgg8 = (NN * 8 + 255) / 256;

    transform_kernel<8, 32><<<gN, 256, 0, stream>>>(nullptr, x, W1, nullptr, dinv, A, 32, NN);
    aggregate_csr<8><<<gAgg8, 256, 0, stream>>>(start, degi, srow, A, B, NN);

    transform_kernel<32, 32><<<gN, 256, 0, stream>>>(B, nullptr, W2, b1, dinv, A, 32, NN);
    aggregate_csr<8><<<gAgg8, 256, 0, stream>>>(start, degi, srow, A, B, NN);

    transform_kernel<32, 32><<<gN, 256, 0, stream>>>(B, nullptr, W3, b2, dinv, A, 32, NN);
    aggregate_csr<8><<<gAgg8, 256, 0, stream>>>(start, degi, srow, A, B, NN);

    transform_kernel<32, 32><<<gN, 256, 0, stream>>>(B, nullptr, W4, b3, dinv, A, 32, NN);
    aggregate_csr<8><<<gAgg8, 256, 0, stream>>>(start, degi, srow, A, B, NN);

    transform_kernel<32, 4><<<gN, 256, 0, stream>>>(B, nullptr, W5, b4, dinv, C, 3, NN);
    aggregate_csr<1><<<gN, 256, 0, stream>>>(start, degi, srow, C, D, NN);

    finalize_kernel<<<(NN * 3 + 255) / 256, 256, 0, stream>>>(D, b5, dinv, out, NN);
}

// Round 6
// 458.439 us; speedup vs baseline: 1.1407x; 1.1407x over previous
//
#include <hip/hip_runtime.h>
#include <hip/hip_bf16.h>

#define NN 100000
#define NE 1600000

// ---- edge dtype detection (proven int32; kept as zero-cost guard) --------

__global__ __launch_bounds__(256) void detect_kernel(const unsigned int* __restrict__ w,
                                                     int* __restrict__ is64) {
    __shared__ int nz;
    if (threadIdx.x == 0) nz = 0;
    __syncthreads();
    if (w[2 * threadIdx.x + 1] != 0) atomicAdd(&nz, 1);
    __syncthreads();
    if (threadIdx.x == 0) *is64 = (nz == 0) ? 1 : 0;
}

static __device__ __forceinline__ int edge_at(const void* ei, int is64, long long pos) {
    return is64 ? (int)((const long long*)ei)[pos] : ((const int*)ei)[pos];
}

// ---- preprocessing -------------------------------------------------------

__global__ __launch_bounds__(256) void deg_kernel(const void* __restrict__ ei,
                                                  const int* __restrict__ is64,
                                                  int* __restrict__ degi, int E) {
    int e = blockIdx.x * 256 + threadIdx.x;
    if (e < E) {
        int c = edge_at(ei, *is64, (long long)E + e);  // col = edge_index[1]
        atomicAdd(&degi[c], 1);
    }
}

__global__ __launch_bounds__(256) void dinv_kernel(const int* __restrict__ degi,
                                                   float* __restrict__ dinv, int N) {
    int i = blockIdx.x * 256 + threadIdx.x;
    if (i < N) dinv[i] = 1.0f / sqrtf((float)degi[i] + 1.0f);  // +1 self-loop
}

// segment start offsets: segment order irrelevant → block-scan + one atomic.
__global__ __launch_bounds__(256) void start_kernel(const int* __restrict__ degi,
                                                    int* __restrict__ start,
                                                    int* __restrict__ cursor,
                                                    int* __restrict__ counter, int N) {
    __shared__ int s[256];
    __shared__ int base;
    int tid = threadIdx.x;
    int i = blockIdx.x * 256 + tid;
    int v = (i < N) ? degi[i] : 0;
    int acc = v;
    s[tid] = v;
    __syncthreads();
    for (int off = 1; off < 256; off <<= 1) {
        int y = (tid >= off) ? s[tid - off] : 0;
        __syncthreads();
        acc += y;
        s[tid] = acc;
        __syncthreads();
    }
    if (tid == 255) base = atomicAdd(counter, acc);
    __syncthreads();
    int excl = base + acc - v;
    if (i < N) { start[i] = excl; cursor[i] = excl; }
}

__global__ __launch_bounds__(256) void scatter_kernel(const void* __restrict__ ei,
                                                      const int* __restrict__ is64,
                                                      int* __restrict__ cursor,
                                                      int* __restrict__ srow, int E) {
    int e = blockIdx.x * 256 + threadIdx.x;
    if (e < E) {
        int f = *is64;
        int r = edge_at(ei, f, e);                    // row (gather source)
        int c = edge_at(ei, f, (long long)E + e);     // col (scatter target)
        int p = atomicAdd(&cursor[c], 1);
        srow[p] = r;
    }
}

// ---- weight folding for layer-1 reorder: W12 = W1@W2, pv = b1@W2 ---------
// Valid because aggregation is linear: A_hat(x W1) = (A_hat x) W1.

__global__ __launch_bounds__(256) void prep_kernel(const float* __restrict__ W1,
                                                   const float* __restrict__ W2,
                                                   const float* __restrict__ b1,
                                                   float* __restrict__ W12,
                                                   float* __restrict__ pv) {
    int tid = threadIdx.x;
    int i = tid >> 5, j = tid & 31;  // 8 x 32
    float s = 0.0f;
    for (int k = 0; k < 32; k++) s += W1[i * 32 + k] * W2[k * 32 + j];
    W12[i * 32 + j] = s;
    if (tid < 32) {
        float t = 0.0f;
        for (int k = 0; k < 32; k++) t += b1[k] * W2[k * 32 + tid];
        pv[tid] = t;
    }
}

// ---- t0 = dinv ⊙ x  (width 8) --------------------------------------------

__global__ __launch_bounds__(256) void scale8_kernel(const float* __restrict__ x,
                                                     const float* __restrict__ dinv,
                                                     float* __restrict__ t0, int N) {
    int tid = blockIdx.x * 256 + threadIdx.x;
    if (tid >= N * 2) return;
    int n = tid >> 1;
    float d = dinv[n];
    float4 v = ((const float4*)x)[tid];
    v.x *= d; v.y *= d; v.z *= d; v.w *= d;
    ((float4*)t0)[tid] = v;
}

// ---- transform with post-matmul bias: t = dinv*((dinv*acc)@W + pv) -------

template <int DIN, int DOUT>
__global__ __launch_bounds__(256) void transform_post_kernel(
    const float* __restrict__ accin, const float* __restrict__ W,
    const float* __restrict__ pv, const float* __restrict__ dinv,
    float* __restrict__ t, int N) {
    __shared__ float Wl[DIN * DOUT];
    __shared__ float pl[DOUT];
    for (int i = threadIdx.x; i < DIN * DOUT; i += 256) Wl[i] = W[i];
    for (int i = threadIdx.x; i < DOUT; i += 256) pl[i] = pv[i];
    __syncthreads();
    int n = blockIdx.x * 256 + threadIdx.x;
    if (n >= N) return;
    float d = dinv[n];
    float h[DIN];
    const float4* a4 = (const float4*)accin + n * (DIN / 4);
#pragma unroll
    for (int k4 = 0; k4 < DIN / 4; k4++) {
        float4 v = a4[k4];
        h[4 * k4 + 0] = d * v.x; h[4 * k4 + 1] = d * v.y;
        h[4 * k4 + 2] = d * v.z; h[4 * k4 + 3] = d * v.w;
    }
    float4 o[DOUT / 4];
#pragma unroll
    for (int j = 0; j < DOUT / 4; j++)
        o[j] = make_float4(pl[4 * j], pl[4 * j + 1], pl[4 * j + 2], pl[4 * j + 3]);
#pragma unroll
    for (int k = 0; k < DIN; k++) {
        float hk = h[k];
        const float4* w4 = (const float4*)&Wl[k * DOUT];
#pragma unroll
        for (int j = 0; j < DOUT / 4; j++) {
            float4 w = w4[j];
            o[j].x += hk * w.x; o[j].y += hk * w.y;
            o[j].z += hk * w.z; o[j].w += hk * w.w;
        }
    }
    float4* t4 = (float4*)t + n * (DOUT / 4);
#pragma unroll
    for (int j = 0; j < DOUT / 4; j++) {
        o[j].x *= d; o[j].y *= d; o[j].z *= d; o[j].w *= d;
        t4[j] = o[j];
    }
}

// ---- transform with input bias: t = dinv*((dinv*acc + bprev)@W) ----------

template <int DIN, int DOUT>
__global__ __launch_bounds__(256) void transform_kernel(
    const float* __restrict__ accin, const float* __restrict__ W,
    const float* __restrict__ bprev, const float* __restrict__ dinv,
    float* __restrict__ t, int wcols, int N) {
    __shared__ float Wl[DIN * DOUT];
    __shared__ float bl[DIN];
    for (int i = threadIdx.x; i < DIN * DOUT; i += 256) {
        int k = i / DOUT, j = i - k * DOUT;
        Wl[i] = (j < wcols) ? W[k * wcols + j] : 0.0f;  // pad W5 cols to 4
    }
    for (int i = threadIdx.x; i < DIN; i += 256) bl[i] = bprev[i];
    __syncthreads();

    int n = blockIdx.x * 256 + threadIdx.x;
    if (n >= N) return;
    float d = dinv[n];
    float h[DIN];
    const float4* a4 = (const float4*)accin + n * (DIN / 4);
#pragma unroll
    for (int k4 = 0; k4 < DIN / 4; k4++) {
        float4 v = a4[k4];
        h[4 * k4 + 0] = d * v.x + bl[4 * k4 + 0];
        h[4 * k4 + 1] = d * v.y + bl[4 * k4 + 1];
        h[4 * k4 + 2] = d * v.z + bl[4 * k4 + 2];
        h[4 * k4 + 3] = d * v.w + bl[4 * k4 + 3];
    }
    float4 o[DOUT / 4];
#pragma unroll
    for (int j = 0; j < DOUT / 4; j++) o[j] = make_float4(0.f, 0.f, 0.f, 0.f);
#pragma unroll
    for (int k = 0; k < DIN; k++) {
        float hk = h[k];
        const float4* w4 = (const float4*)&Wl[k * DOUT];
#pragma unroll
        for (int j = 0; j < DOUT / 4; j++) {
            float4 w = w4[j];
            o[j].x += hk * w.x; o[j].y += hk * w.y;
            o[j].z += hk * w.z; o[j].w += hk * w.w;
        }
    }
    float4* t4 = (float4*)t + n * (DOUT / 4);
#pragma unroll
    for (int j = 0; j < DOUT / 4; j++) {
        o[j].x *= d; o[j].y *= d; o[j].z *= d; o[j].w *= d;
        t4[j] = o[j];
    }
}

// ---- CSR aggregation, unroll-4 with independent accumulators -------------
// acc[c] = t[c] + sum over incoming edges of t[row]. NC float4 chunks/node.

template <int NC>
__global__ __launch_bounds__(256) void aggregate_csr(
    const int* __restrict__ start, const int* __restrict__ degi,
    const int* __restrict__ srow, const float* __restrict__ t,
    float* __restrict__ acc, int N) {
    int tid = blockIdx.x * 256 + threadIdx.x;
    int c = tid / NC, j = tid - (tid / NC) * NC;
    if (c >= N) return;
    int s = start[c];
    int d = degi[c];
    const float4* tv = (const float4*)t;
    float4 a0 = tv[c * NC + j];  // self-loop term
    float4 a1 = make_float4(0.f, 0.f, 0.f, 0.f);
    float4 a2 = make_float4(0.f, 0.f, 0.f, 0.f);
    float4 a3 = make_float4(0.f, 0.f, 0.f, 0.f);
    int i = 0;
    for (; i + 4 <= d; i += 4) {
        int r0 = srow[s + i + 0];
        int r1 = srow[s + i + 1];
        int r2 = srow[s + i + 2];
        int r3 = srow[s + i + 3];
        float4 v0 = tv[r0 * NC + j];
        float4 v1 = tv[r1 * NC + j];
        float4 v2 = tv[r2 * NC + j];
        float4 v3 = tv[r3 * NC + j];
        a0.x += v0.x; a0.y += v0.y; a0.z += v0.z; a0.w += v0.w;
        a1.x += v1.x; a1.y += v1.y; a1.z += v1.z; a1.w += v1.w;
        a2.x += v2.x; a2.y += v2.y; a2.z += v2.z; a2.w += v2.w;
        a3.x += v3.x; a3.y += v3.y; a3.z += v3.z; a3.w += v3.w;
    }
    for (; i < d; i++) {
        int r = srow[s + i];
        float4 v = tv[r * NC + j];
        a0.x += v.x; a0.y += v.y; a0.z += v.z; a0.w += v.w;
    }
    a0.x += a1.x + a2.x + a3.x;
    a0.y += a1.y + a2.y + a3.y;
    a0.z += a1.z + a2.z + a3.z;
    a0.w += a1.w + a2.w + a3.w;
    ((float4*)acc)[c * NC + j] = a0;
}

// ---- final: out fp32 [N,3] ------------------------------------------------

__global__ __launch_bounds__(256) void finalize_kernel(
    const float* __restrict__ acc4, const float* __restrict__ b5,
    const float* __restrict__ dinv, float* __restrict__ out, int N) {
    int i = blockIdx.x * 256 + threadIdx.x;
    if (i >= N * 3) return;
    int n = i / 3, j = i - n * 3;
    out[i] = dinv[n] * acc4[n * 4 + j] + b5[j];
}

// ---- launch --------------------------------------------------------------

extern "C" void kernel_launch(void* const* d_in, const int* in_sizes, int n_in,
                              void* d_out, int out_size, void* d_ws, size_t ws_size,
                              hipStream_t stream) {
    const float* x  = (const float*)d_in[0];
    const void*  ei = d_in[1];
    const float* W1 = (const float*)d_in[2];  const float* b1 = (const float*)d_in[3];
    const float* W2 = (const float*)d_in[4];  const float* b2 = (const float*)d_in[5];
    const float* W3 = (const float*)d_in[6];  const float* b3 = (const float*)d_in[7];
    const float* W4 = (const float*)d_in[8];  const float* b4 = (const float*)d_in[9];
    const float* W5 = (const float*)d_in[10]; const float* b5 = (const float*)d_in[11];
    float* out = (float*)d_out;

    char* p = (char*)d_ws;
    auto alloc = [&](size_t bytes) {
        char* r = p;
        p += (bytes + 255) & ~(size_t)255;
        return r;
    };
    int*   degi    = (int*)alloc(NN * 4);
    float* dinv    = (float*)alloc(NN * 4);
    int*   start   = (int*)alloc(NN * 4);
    int*   cursor  = (int*)alloc(NN * 4);
    int*   counter = (int*)alloc(256);
    int*   is64    = (int*)alloc(256);
    float* W12     = (float*)alloc(8 * 32 * 4);
    float* pv      = (float*)alloc(32 * 4);
    int*   srow    = (int*)alloc((size_t)NE * 4);
    float* A       = (float*)alloc((size_t)NN * 32 * 4);  // t buffers
    float* B       = (float*)alloc((size_t)NN * 32 * 4);  // acc buffers
    float* C       = (float*)alloc((size_t)NN * 4 * 4);   // t, layer 5 (3->4 pad)
    float* D       = (float*)alloc((size_t)NN * 4 * 4);   // acc, layer 5
    if ((size_t)(p - (char*)d_ws) > ws_size) return;      // canary: zero output

    hipMemsetAsync(degi, 0, NN * 4, stream);
    hipMemsetAsync(counter, 0, 4, stream);

    int gE = (NE + 255) / 256, gN = (NN + 255) / 256;
    detect_kernel<<<1, 256, 0, stream>>>((const unsigned int*)ei, is64);
    deg_kernel<<<gE, 256, 0, stream>>>(ei, is64, degi, NE);
    dinv_kernel<<<gN, 256, 0, stream>>>(degi, dinv, NN);
    start_kernel<<<gN, 256, 0, stream>>>(degi, start, cursor, counter, NN);
    scatter_kernel<<<gE, 256, 0, stream>>>(ei, is64, cursor, srow, NE);
    prep_kernel<<<1, 256, 0, stream>>>(W1, W2, b1, W12, pv);

    int gAgg8 = (NN * 8 + 255) / 256;
    int gAgg2 = (NN * 2 + 255) / 256;

    // Layer 1 (reordered): aggregate width-8 x, then fold W1@W2 transform.
    scale8_kernel<<<gAgg2, 256, 0, stream>>>(x, dinv, A, NN);
    aggregate_csr<2><<<gAgg2, 256, 0, stream>>>(start, degi, srow, A, B, NN);

    // Layer 2: t2 = dinv*((dinv*acc0)@W12 + b1@W2)
    transform_post_kernel<8, 32><<<gN, 256, 0, stream>>>(B, W12, pv, dinv, A, NN);
    aggregate_csr<8><<<gAgg8, 256, 0, stream>>>(start, degi, srow, A, B, NN);

    // Layer 3
    transform_kernel<32, 32><<<gN, 256, 0, stream>>>(B, W3, b2, dinv, A, 32, NN);
    aggregate_csr<8><<<gAgg8, 256, 0, stream>>>(start, degi, srow, A, B, NN);

    // Layer 4
    transform_kernel<32, 32><<<gN, 256, 0, stream>>>(B, W4, b3, dinv, A, 32, NN);
    aggregate_csr<8><<<gAgg8, 256, 0, stream>>>(start, degi, srow, A, B, NN);

    // Layer 5 (padded dout 3->4)
    transform_kernel<32, 4><<<gN, 256, 0, stream>>>(B, W5, b4, dinv, C, 3, NN);
    aggregate_csr<1><<<gN, 256, 0, stream>>>(start, degi, srow, C, D, NN);

    finalize_kernel<<<(NN * 3 + 255) / 256, 256, 0, stream>>>(D, b5, dinv, out, NN);
}

// Round 7
// 305.847 us; speedup vs baseline: 1.7098x; 1.4989x over previous
//
#include <hip/hip_runtime.h>
#include <hip/hip_bf16.h>

#define NN 100000
#define NE 1600000
#define NB 391        // ceil(NN/256) buckets, bucket = col >> 8
#define EPB 4096      // edges per block in bucket passes
#define NBLK 391      // ceil(NE/EPB)

// ---- edge dtype detection (proven int32; kept as zero-cost guard) --------

__global__ __launch_bounds__(256) void detect_kernel(const unsigned int* __restrict__ w,
                                                     int* __restrict__ is64) {
    __shared__ int nz;
    if (threadIdx.x == 0) nz = 0;
    __syncthreads();
    if (w[2 * threadIdx.x + 1] != 0) atomicAdd(&nz, 1);
    __syncthreads();
    if (threadIdx.x == 0) *is64 = (nz == 0) ? 1 : 0;
}

static __device__ __forceinline__ int edge_at(const void* ei, int is64, long long pos) {
    return is64 ? (int)((const long long*)ei)[pos] : ((const int*)ei)[pos];
}

// ---- pass A: per-block LDS bucket histogram ------------------------------

__global__ __launch_bounds__(256) void bucket_count_kernel(const void* __restrict__ ei,
                                                           const int* __restrict__ is64,
                                                           int* __restrict__ bcount, int E) {
    __shared__ int lc[NB];
    int tid = threadIdx.x;
    for (int i = tid; i < NB; i += 256) lc[i] = 0;
    __syncthreads();
    int f = *is64;
    long long base = (long long)blockIdx.x * EPB;
    for (int k = 0; k < EPB / 256; k++) {
        long long e = base + k * 256 + tid;
        if (e < E) {
            int c = edge_at(ei, f, (long long)E + e);
            atomicAdd(&lc[c >> 8], 1);
        }
    }
    __syncthreads();
    for (int i = tid; i < NB; i += 256)
        if (lc[i]) atomicAdd(&bcount[i], lc[i]);
}

// ---- pass B: scan bucket counts (1 block) --------------------------------

__global__ __launch_bounds__(512) void bucket_scan_kernel(const int* __restrict__ bcount,
                                                          int* __restrict__ bstart,
                                                          int* __restrict__ bcursor, int E) {
    __shared__ int s[512];
    int tid = threadIdx.x;
    int v = (tid < NB) ? bcount[tid] : 0;
    int acc = v;
    s[tid] = v;
    __syncthreads();
    for (int off = 1; off < 512; off <<= 1) {
        int y = (tid >= off) ? s[tid - off] : 0;
        __syncthreads();
        acc += y;
        s[tid] = acc;
        __syncthreads();
    }
    if (tid < NB) {
        int excl = acc - v;
        bstart[tid] = excl;
        bcursor[tid] = excl;
    }
    if (tid == 0) bstart[NB] = E;
}

// ---- pass C: block-local bucket grouping + coalesced flush ---------------
// epacked[i] = (col&255)<<24 | row   (row < 2^24)

__global__ __launch_bounds__(256) void bucket_scatter_kernel(const void* __restrict__ ei,
                                                             const int* __restrict__ is64,
                                                             int* __restrict__ bcursor,
                                                             unsigned int* __restrict__ epacked,
                                                             int E) {
    __shared__ int lcount[NB];
    __shared__ int lstart[NB];
    __shared__ int lcur[NB];
    __shared__ int gbase[NB];
    __shared__ int ps[256];
    __shared__ unsigned int slotv[EPB];
    __shared__ unsigned short slotb[EPB];
    int tid = threadIdx.x;
    for (int i = tid; i < NB; i += 256) lcount[i] = 0;
    __syncthreads();
    int f = *is64;
    long long base = (long long)blockIdx.x * EPB;
    int r[EPB / 256], c[EPB / 256];
    for (int k = 0; k < EPB / 256; k++) {
        long long e = base + (long long)k * 256 + tid;
        if (e < E) {
            r[k] = edge_at(ei, f, e);
            c[k] = edge_at(ei, f, (long long)E + e);
            atomicAdd(&lcount[c[k] >> 8], 1);
        } else {
            r[k] = -1;
        }
    }
    __syncthreads();
    // pairwise exclusive scan of lcount (512-padded, 2 elems/thread)
    int e0 = (2 * tid < NB) ? lcount[2 * tid] : 0;
    int e1 = (2 * tid + 1 < NB) ? lcount[2 * tid + 1] : 0;
    int sum = e0 + e1, acc = sum;
    ps[tid] = sum;
    __syncthreads();
    for (int off = 1; off < 256; off <<= 1) {
        int y = (tid >= off) ? ps[tid - off] : 0;
        __syncthreads();
        acc += y;
        ps[tid] = acc;
        __syncthreads();
    }
    int excl = acc - sum;
    if (2 * tid < NB) lstart[2 * tid] = excl;
    if (2 * tid + 1 < NB) lstart[2 * tid + 1] = excl + e0;
    __syncthreads();
    for (int i = tid; i < NB; i += 256) lcur[i] = lstart[i];
    __syncthreads();
    // group edges by bucket in LDS
    for (int k = 0; k < EPB / 256; k++) {
        if (r[k] >= 0) {
            int b = c[k] >> 8;
            int pos = atomicAdd(&lcur[b], 1);
            slotv[pos] = ((unsigned)(c[k] & 255) << 24) | (unsigned)r[k];
            slotb[pos] = (unsigned short)b;
        }
    }
    __syncthreads();
    // reserve global slices, one atomic per touched bucket
    for (int i = tid; i < NB; i += 256) {
        int cnt = lcount[i];
        gbase[i] = cnt ? atomicAdd(&bcursor[i], cnt) : 0;
    }
    __syncthreads();
    // coalesced-ish flush (runs of same bucket are contiguous)
    long long rem = (long long)E - base;
    int total = (rem < EPB) ? (int)rem : EPB;
    for (int s2 = tid; s2 < total; s2 += 256) {
        int b = slotb[s2];
        int within = s2 - lstart[b];
        epacked[gbase[b] + within] = slotv[s2];
    }
}

// ---- pass D: per-bucket CSR build + start/deg/dinv (zero global atomics) --

__global__ __launch_bounds__(256) void bucket_csr_kernel(const unsigned int* __restrict__ epacked,
                                                         const int* __restrict__ bstart,
                                                         int* __restrict__ start,
                                                         int* __restrict__ degi,
                                                         float* __restrict__ dinv,
                                                         int* __restrict__ srow, int N) {
    __shared__ int lcount[256];
    __shared__ int lcur[256];
    __shared__ int ss[256];
    int b = blockIdx.x;
    int tid = threadIdx.x;
    int s0 = bstart[b];
    int cnt = bstart[b + 1] - s0;
    lcount[tid] = 0;
    __syncthreads();
    for (int i = tid; i < cnt; i += 256) {
        unsigned int v = epacked[s0 + i];
        atomicAdd(&lcount[v >> 24], 1);
    }
    __syncthreads();
    int myc = lcount[tid];
    int acc = myc;
    ss[tid] = myc;
    __syncthreads();
    for (int off = 1; off < 256; off <<= 1) {
        int y = (tid >= off) ? ss[tid - off] : 0;
        __syncthreads();
        acc += y;
        ss[tid] = acc;
        __syncthreads();
    }
    int excl = acc - myc;
    lcur[tid] = excl;
    int col = (b << 8) + tid;
    if (col < N) {
        start[col] = s0 + excl;
        degi[col] = myc;
        dinv[col] = 1.0f / sqrtf((float)myc + 1.0f);  // +1 self-loop
    }
    __syncthreads();
    for (int i = tid; i < cnt; i += 256) {
        unsigned int v = epacked[s0 + i];
        int p = atomicAdd(&lcur[v >> 24], 1);
        srow[s0 + p] = (int)(v & 0xFFFFFFu >> 8 << 8) | (int)(v & 0xFFFFFF);  // row
    }
}

// ---- weight folding for layer-1 reorder: W12 = W1@W2, pv = b1@W2 ---------

__global__ __launch_bounds__(256) void prep_kernel(const float* __restrict__ W1,
                                                   const float* __restrict__ W2,
                                                   const float* __restrict__ b1,
                                                   float* __restrict__ W12,
                                                   float* __restrict__ pv) {
    int tid = threadIdx.x;
    int i = tid >> 5, j = tid & 31;  // 8 x 32
    float s = 0.0f;
    for (int k = 0; k < 32; k++) s += W1[i * 32 + k] * W2[k * 32 + j];
    W12[i * 32 + j] = s;
    if (tid < 32) {
        float t = 0.0f;
        for (int k = 0; k < 32; k++) t += b1[k] * W2[k * 32 + tid];
        pv[tid] = t;
    }
}

// ---- t0 = dinv ⊙ x  (width 8) --------------------------------------------

__global__ __launch_bounds__(256) void scale8_kernel(const float* __restrict__ x,
                                                     const float* __restrict__ dinv,
                                                     float* __restrict__ t0, int N) {
    int tid = blockIdx.x * 256 + threadIdx.x;
    if (tid >= N * 2) return;
    int n = tid >> 1;
    float d = dinv[n];
    float4 v = ((const float4*)x)[tid];
    v.x *= d; v.y *= d; v.z *= d; v.w *= d;
    ((float4*)t0)[tid] = v;
}

// ---- transform with post-matmul bias: t = dinv*((dinv*acc)@W + pv) -------

template <int DIN, int DOUT>
__global__ __launch_bounds__(256) void transform_post_kernel(
    const float* __restrict__ accin, const float* __restrict__ W,
    const float* __restrict__ pv, const float* __restrict__ dinv,
    float* __restrict__ t, int N) {
    __shared__ float Wl[DIN * DOUT];
    __shared__ float pl[DOUT];
    for (int i = threadIdx.x; i < DIN * DOUT; i += 256) Wl[i] = W[i];
    for (int i = threadIdx.x; i < DOUT; i += 256) pl[i] = pv[i];
    __syncthreads();
    int n = blockIdx.x * 256 + threadIdx.x;
    if (n >= N) return;
    float d = dinv[n];
    float h[DIN];
    const float4* a4 = (const float4*)accin + n * (DIN / 4);
#pragma unroll
    for (int k4 = 0; k4 < DIN / 4; k4++) {
        float4 v = a4[k4];
        h[4 * k4 + 0] = d * v.x; h[4 * k4 + 1] = d * v.y;
        h[4 * k4 + 2] = d * v.z; h[4 * k4 + 3] = d * v.w;
    }
    float4 o[DOUT / 4];
#pragma unroll
    for (int j = 0; j < DOUT / 4; j++)
        o[j] = make_float4(pl[4 * j], pl[4 * j + 1], pl[4 * j + 2], pl[4 * j + 3]);
#pragma unroll
    for (int k = 0; k < DIN; k++) {
        float hk = h[k];
        const float4* w4 = (const float4*)&Wl[k * DOUT];
#pragma unroll
        for (int j = 0; j < DOUT / 4; j++) {
            float4 w = w4[j];
            o[j].x += hk * w.x; o[j].y += hk * w.y;
            o[j].z += hk * w.z; o[j].w += hk * w.w;
        }
    }
    float4* t4 = (float4*)t + n * (DOUT / 4);
#pragma unroll
    for (int j = 0; j < DOUT / 4; j++) {
        o[j].x *= d; o[j].y *= d; o[j].z *= d; o[j].w *= d;
        t4[j] = o[j];
    }
}

// ---- transform with input bias: t = dinv*((dinv*acc + bprev)@W) ----------

template <int DIN, int DOUT>
__global__ __launch_bounds__(256) void transform_kernel(
    const float* __restrict__ accin, const float* __restrict__ W,
    const float* __restrict__ bprev, const float* __restrict__ dinv,
    float* __restrict__ t, int wcols, int N) {
    __shared__ float Wl[DIN * DOUT];
    __shared__ float bl[DIN];
    for (int i = threadIdx.x; i < DIN * DOUT; i += 256) {
        int k = i / DOUT, j = i - k * DOUT;
        Wl[i] = (j < wcols) ? W[k * wcols + j] : 0.0f;  // pad W5 cols to 4
    }
    for (int i = threadIdx.x; i < DIN; i += 256) bl[i] = bprev[i];
    __syncthreads();

    int n = blockIdx.x * 256 + threadIdx.x;
    if (n >= N) return;
    float d = dinv[n];
    float h[DIN];
    const float4* a4 = (const float4*)accin + n * (DIN / 4);
#pragma unroll
    for (int k4 = 0; k4 < DIN / 4; k4++) {
        float4 v = a4[k4];
        h[4 * k4 + 0] = d * v.x + bl[4 * k4 + 0];
        h[4 * k4 + 1] = d * v.y + bl[4 * k4 + 1];
        h[4 * k4 + 2] = d * v.z + bl[4 * k4 + 2];
        h[4 * k4 + 3] = d * v.w + bl[4 * k4 + 3];
    }
    float4 o[DOUT / 4];
#pragma unroll
    for (int j = 0; j < DOUT / 4; j++) o[j] = make_float4(0.f, 0.f, 0.f, 0.f);
#pragma unroll
    for (int k = 0; k < DIN; k++) {
        float hk = h[k];
        const float4* w4 = (const float4*)&Wl[k * DOUT];
#pragma unroll
        for (int j = 0; j < DOUT / 4; j++) {
            float4 w = w4[j];
            o[j].x += hk * w.x; o[j].y += hk * w.y;
            o[j].z += hk * w.z; o[j].w += hk * w.w;
        }
    }
    float4* t4 = (float4*)t + n * (DOUT / 4);
#pragma unroll
    for (int j = 0; j < DOUT / 4; j++) {
        o[j].x *= d; o[j].y *= d; o[j].z *= d; o[j].w *= d;
        t4[j] = o[j];
    }
}

// ---- CSR aggregation, unroll-4 with independent accumulators -------------

template <int NC>
__global__ __launch_bounds__(256) void aggregate_csr(
    const int* __restrict__ start, const int* __restrict__ degi,
    const int* __restrict__ srow, const float* __restrict__ t,
    float* __restrict__ acc, int N) {
    int tid = blockIdx.x * 256 + threadIdx.x;
    int c = tid / NC, j = tid - (tid / NC) * NC;
    if (c >= N) return;
    int s = start[c];
    int d = degi[c];
    const float4* tv = (const float4*)t;
    float4 a0 = tv[c * NC + j];  // self-loop term
    float4 a1 = make_float4(0.f, 0.f, 0.f, 0.f);
    float4 a2 = make_float4(0.f, 0.f, 0.f, 0.f);
    float4 a3 = make_float4(0.f, 0.f, 0.f, 0.f);
    int i = 0;
    for (; i + 4 <= d; i += 4) {
        int r0 = srow[s + i + 0];
        int r1 = srow[s + i + 1];
        int r2 = srow[s + i + 2];
        int r3 = srow[s + i + 3];
        float4 v0 = tv[r0 * NC + j];
        float4 v1 = tv[r1 * NC + j];
        float4 v2 = tv[r2 * NC + j];
        float4 v3 = tv[r3 * NC + j];
        a0.x += v0.x; a0.y += v0.y; a0.z += v0.z; a0.w += v0.w;
        a1.x += v1.x; a1.y += v1.y; a1.z += v1.z; a1.w += v1.w;
        a2.x += v2.x; a2.y += v2.y; a2.z += v2.z; a2.w += v2.w;
        a3.x += v3.x; a3.y += v3.y; a3.z += v3.z; a3.w += v3.w;
    }
    for (; i < d; i++) {
        int r = srow[s + i];
        float4 v = tv[r * NC + j];
        a0.x += v.x; a0.y += v.y; a0.z += v.z; a0.w += v.w;
    }
    a0.x += a1.x + a2.x + a3.x;
    a0.y += a1.y + a2.y + a3.y;
    a0.z += a1.z + a2.z + a3.z;
    a0.w += a1.w + a2.w + a3.w;
    ((float4*)acc)[c * NC + j] = a0;
}

// ---- final: out fp32 [N,3] ------------------------------------------------

__global__ __launch_bounds__(256) void finalize_kernel(
    const float* __restrict__ acc4, const float* __restrict__ b5,
    const float* __restrict__ dinv, float* __restrict__ out, int N) {
    int i = blockIdx.x * 256 + threadIdx.x;
    if (i >= N * 3) return;
    int n = i / 3, j = i - n * 3;
    out[i] = dinv[n] * acc4[n * 4 + j] + b5[j];
}

// ---- launch --------------------------------------------------------------

extern "C" void kernel_launch(void* const* d_in, const int* in_sizes, int n_in,
                              void* d_out, int out_size, void* d_ws, size_t ws_size,
                              hipStream_t stream) {
    const float* x  = (const float*)d_in[0];
    const void*  ei = d_in[1];
    const float* W1 = (const float*)d_in[2];  const float* b1 = (const float*)d_in[3];
    const float* W2 = (const float*)d_in[4];  const float* b2 = (const float*)d_in[5];
    const float* W3 = (const float*)d_in[6];  const float* b3 = (const float*)d_in[7];
    const float* W4 = (const float*)d_in[8];  const float* b4 = (const float*)d_in[9];
    const float* W5 = (const float*)d_in[10]; const float* b5 = (const float*)d_in[11];
    float* out = (float*)d_out;

    char* p = (char*)d_ws;
    auto alloc = [&](size_t bytes) {
        char* r = p;
        p += (bytes + 255) & ~(size_t)255;
        return r;
    };
    int*   degi    = (int*)alloc(NN * 4);
    float* dinv    = (float*)alloc(NN * 4);
    int*   start   = (int*)alloc(NN * 4);
    int*   is64    = (int*)alloc(256);
    int*   bcount  = (int*)alloc(NB * 4);
    int*   bstart  = (int*)alloc((NB + 1) * 4);
    int*   bcursor = (int*)alloc(NB * 4);
    float* W12     = (float*)alloc(8 * 32 * 4);
    float* pv      = (float*)alloc(32 * 4);
    unsigned int* epacked = (unsigned int*)alloc((size_t)NE * 4);
    int*   srow    = (int*)alloc((size_t)NE * 4);
    float* A       = (float*)alloc((size_t)NN * 32 * 4);  // t buffers
    float* B       = (float*)alloc((size_t)NN * 32 * 4);  // acc buffers
    float* C       = (float*)alloc((size_t)NN * 4 * 4);   // t, layer 5 (3->4 pad)
    float* D       = (float*)alloc((size_t)NN * 4 * 4);   // acc, layer 5
    if ((size_t)(p - (char*)d_ws) > ws_size) return;      // canary: zero output

    hipMemsetAsync(bcount, 0, NB * 4, stream);

    int gN = (NN + 255) / 256;
    detect_kernel<<<1, 256, 0, stream>>>((const unsigned int*)ei, is64);
    bucket_count_kernel<<<NBLK, 256, 0, stream>>>(ei, is64, bcount, NE);
    bucket_scan_kernel<<<1, 512, 0, stream>>>(bcount, bstart, bcursor, NE);
    bucket_scatter_kernel<<<NBLK, 256, 0, stream>>>(ei, is64, bcursor, epacked, NE);
    bucket_csr_kernel<<<NB, 256, 0, stream>>>(epacked, bstart, start, degi, dinv, srow, NN);
    prep_kernel<<<1, 256, 0, stream>>>(W1, W2, b1, W12, pv);

    int gAgg8 = (NN * 8 + 255) / 256;
    int gAgg2 = (NN * 2 + 255) / 256;

    // Layer 1 (reordered): aggregate width-8 x, then fold W1@W2 transform.
    scale8_kernel<<<gAgg2, 256, 0, stream>>>(x, dinv, A, NN);
    aggregate_csr<2><<<gAgg2, 256, 0, stream>>>(start, degi, srow, A, B, NN);

    // Layer 2: t2 = dinv*((dinv*acc0)@W12 + b1@W2)
    transform_post_kernel<8, 32><<<gN, 256, 0, stream>>>(B, W12, pv, dinv, A, NN);
    aggregate_csr<8><<<gAgg8, 256, 0, stream>>>(start, degi, srow, A, B, NN);

    // Layer 3
    transform_kernel<32, 32><<<gN, 256, 0, stream>>>(B, W3, b2, dinv, A, 32, NN);
    aggregate_csr<8><<<gAgg8, 256, 0, stream>>>(start, degi, srow, A, B, NN);

    // Layer 4
    transform_kernel<32, 32><<<gN, 256, 0, stream>>>(B, W4, b3, dinv, A, 32, NN);
    aggregate_csr<8><<<gAgg8, 256, 0, stream>>>(start, degi, srow, A, B, NN);

    // Layer 5 (padded dout 3->4)
    transform_kernel<32, 4><<<gN, 256, 0, stream>>>(B, W5, b4, dinv, C, 3, NN);
    aggregate_csr<1><<<gN, 256, 0, stream>>>(start, degi, srow, C, D, NN);

    finalize_kernel<<<(NN * 3 + 255) / 256, 256, 0, stream>>>(D, b5, dinv, out, NN);
}

// Round 8
// 289.587 us; speedup vs baseline: 1.8058x; 1.0561x over previous
//
#include <hip/hip_runtime.h>
#include <hip/hip_bf16.h>

#define NN 100000
#define NE 1600000
#define NB 391        // ceil(NN/256) buckets, bucket = col >> 8
#define EPB 4096      // edges per block in bucket passes
#define NBLK 391      // ceil(NE/EPB)

// ---- bf16 helpers (bit-level, RNE) ---------------------------------------

static __device__ __forceinline__ unsigned short f2bf(float f) {
    unsigned u = __float_as_uint(f);
    unsigned r = 0x7FFFu + ((u >> 16) & 1u);
    return (unsigned short)((u + r) >> 16);
}
static __device__ __forceinline__ float bf2f(unsigned short h) {
    return __uint_as_float((unsigned)h << 16);
}
static __device__ __forceinline__ float4 bf2f4(ushort4 v) {
    return make_float4(bf2f(v.x), bf2f(v.y), bf2f(v.z), bf2f(v.w));
}

// ---- edge dtype detection (proven int32; kept as zero-cost guard) --------

__global__ __launch_bounds__(256) void detect_kernel(const unsigned int* __restrict__ w,
                                                     int* __restrict__ is64) {
    __shared__ int nz;
    if (threadIdx.x == 0) nz = 0;
    __syncthreads();
    if (w[2 * threadIdx.x + 1] != 0) atomicAdd(&nz, 1);
    __syncthreads();
    if (threadIdx.x == 0) *is64 = (nz == 0) ? 1 : 0;
}

static __device__ __forceinline__ int edge_at(const void* ei, int is64, long long pos) {
    return is64 ? (int)((const long long*)ei)[pos] : ((const int*)ei)[pos];
}

// ---- pass A: per-block LDS bucket histogram ------------------------------

__global__ __launch_bounds__(256) void bucket_count_kernel(const void* __restrict__ ei,
                                                           const int* __restrict__ is64,
                                                           int* __restrict__ bcount, int E) {
    __shared__ int lc[NB];
    int tid = threadIdx.x;
    for (int i = tid; i < NB; i += 256) lc[i] = 0;
    __syncthreads();
    int f = *is64;
    long long base = (long long)blockIdx.x * EPB;
    for (int k = 0; k < EPB / 256; k++) {
        long long e = base + k * 256 + tid;
        if (e < E) {
            int c = edge_at(ei, f, (long long)E + e);
            atomicAdd(&lc[c >> 8], 1);
        }
    }
    __syncthreads();
    for (int i = tid; i < NB; i += 256)
        if (lc[i]) atomicAdd(&bcount[i], lc[i]);
}

// ---- pass B: scan bucket counts (1 block) --------------------------------

__global__ __launch_bounds__(512) void bucket_scan_kernel(const int* __restrict__ bcount,
                                                          int* __restrict__ bstart,
                                                          int* __restrict__ bcursor, int E) {
    __shared__ int s[512];
    int tid = threadIdx.x;
    int v = (tid < NB) ? bcount[tid] : 0;
    int acc = v;
    s[tid] = v;
    __syncthreads();
    for (int off = 1; off < 512; off <<= 1) {
        int y = (tid >= off) ? s[tid - off] : 0;
        __syncthreads();
        acc += y;
        s[tid] = acc;
        __syncthreads();
    }
    if (tid < NB) {
        int excl = acc - v;
        bstart[tid] = excl;
        bcursor[tid] = excl;
    }
    if (tid == 0) bstart[NB] = E;
}

// ---- pass C: block-local bucket grouping + coalesced flush ---------------
// epacked[i] = (col&255)<<24 | row   (row < 2^24)

__global__ __launch_bounds__(256) void bucket_scatter_kernel(const void* __restrict__ ei,
                                                             const int* __restrict__ is64,
                                                             int* __restrict__ bcursor,
                                                             unsigned int* __restrict__ epacked,
                                                             int E) {
    __shared__ int lcount[NB];
    __shared__ int lstart[NB];
    __shared__ int lcur[NB];
    __shared__ int gbase[NB];
    __shared__ int ps[256];
    __shared__ unsigned int slotv[EPB];
    __shared__ unsigned short slotb[EPB];
    int tid = threadIdx.x;
    for (int i = tid; i < NB; i += 256) lcount[i] = 0;
    __syncthreads();
    int f = *is64;
    long long base = (long long)blockIdx.x * EPB;
    int r[EPB / 256], c[EPB / 256];
    for (int k = 0; k < EPB / 256; k++) {
        long long e = base + (long long)k * 256 + tid;
        if (e < E) {
            r[k] = edge_at(ei, f, e);
            c[k] = edge_at(ei, f, (long long)E + e);
            atomicAdd(&lcount[c[k] >> 8], 1);
        } else {
            r[k] = -1;
        }
    }
    __syncthreads();
    // pairwise exclusive scan of lcount (512-padded, 2 elems/thread)
    int e0 = (2 * tid < NB) ? lcount[2 * tid] : 0;
    int e1 = (2 * tid + 1 < NB) ? lcount[2 * tid + 1] : 0;
    int sum = e0 + e1, acc = sum;
    ps[tid] = sum;
    __syncthreads();
    for (int off = 1; off < 256; off <<= 1) {
        int y = (tid >= off) ? ps[tid - off] : 0;
        __syncthreads();
        acc += y;
        ps[tid] = acc;
        __syncthreads();
    }
    int excl = acc - sum;
    if (2 * tid < NB) lstart[2 * tid] = excl;
    if (2 * tid + 1 < NB) lstart[2 * tid + 1] = excl + e0;
    __syncthreads();
    for (int i = tid; i < NB; i += 256) lcur[i] = lstart[i];
    __syncthreads();
    // group edges by bucket in LDS
    for (int k = 0; k < EPB / 256; k++) {
        if (r[k] >= 0) {
            int b = c[k] >> 8;
            int pos = atomicAdd(&lcur[b], 1);
            slotv[pos] = ((unsigned)(c[k] & 255) << 24) | (unsigned)r[k];
            slotb[pos] = (unsigned short)b;
        }
    }
    __syncthreads();
    // reserve global slices, one atomic per touched bucket
    for (int i = tid; i < NB; i += 256) {
        int cnt = lcount[i];
        gbase[i] = cnt ? atomicAdd(&bcursor[i], cnt) : 0;
    }
    __syncthreads();
    // coalesced-ish flush (runs of same bucket are contiguous)
    long long rem = (long long)E - base;
    int total = (rem < EPB) ? (int)rem : EPB;
    for (int s2 = tid; s2 < total; s2 += 256) {
        int b = slotb[s2];
        int within = s2 - lstart[b];
        epacked[gbase[b] + within] = slotv[s2];
    }
}

// ---- pass D: per-bucket CSR build + start/deg/dinv (zero global atomics) --

__global__ __launch_bounds__(256) void bucket_csr_kernel(const unsigned int* __restrict__ epacked,
                                                         const int* __restrict__ bstart,
                                                         int* __restrict__ start,
                                                         int* __restrict__ degi,
                                                         float* __restrict__ dinv,
                                                         int* __restrict__ srow, int N) {
    __shared__ int lcount[256];
    __shared__ int lcur[256];
    __shared__ int ss[256];
    int b = blockIdx.x;
    int tid = threadIdx.x;
    int s0 = bstart[b];
    int cnt = bstart[b + 1] - s0;
    lcount[tid] = 0;
    __syncthreads();
    for (int i = tid; i < cnt; i += 256) {
        unsigned int v = epacked[s0 + i];
        atomicAdd(&lcount[v >> 24], 1);
    }
    __syncthreads();
    int myc = lcount[tid];
    int acc = myc;
    ss[tid] = myc;
    __syncthreads();
    for (int off = 1; off < 256; off <<= 1) {
        int y = (tid >= off) ? ss[tid - off] : 0;
        __syncthreads();
        acc += y;
        ss[tid] = acc;
        __syncthreads();
    }
    int excl = acc - myc;
    lcur[tid] = excl;
    int col = (b << 8) + tid;
    if (col < N) {
        start[col] = s0 + excl;
        degi[col] = myc;
        dinv[col] = 1.0f / sqrtf((float)myc + 1.0f);  // +1 self-loop
    }
    __syncthreads();
    for (int i = tid; i < cnt; i += 256) {
        unsigned int v = epacked[s0 + i];
        int p = atomicAdd(&lcur[v >> 24], 1);
        srow[s0 + p] = (int)(v & 0xFFFFFFu);  // row
    }
}

// ---- weight folding for layer-1 reorder: W12 = W1@W2, pv = b1@W2 ---------

__global__ __launch_bounds__(256) void prep_kernel(const float* __restrict__ W1,
                                                   const float* __restrict__ W2,
                                                   const float* __restrict__ b1,
                                                   float* __restrict__ W12,
                                                   float* __restrict__ pv) {
    int tid = threadIdx.x;
    int i = tid >> 5, j = tid & 31;  // 8 x 32
    float s = 0.0f;
    for (int k = 0; k < 32; k++) s += W1[i * 32 + k] * W2[k * 32 + j];
    W12[i * 32 + j] = s;
    if (tid < 32) {
        float t = 0.0f;
        for (int k = 0; k < 32; k++) t += b1[k] * W2[k * 32 + tid];
        pv[tid] = t;
    }
}

// ---- t0 = dinv ⊙ x  (width 8, fp32 — input stays full precision) ---------

__global__ __launch_bounds__(256) void scale8_kernel(const float* __restrict__ x,
                                                     const float* __restrict__ dinv,
                                                     float* __restrict__ t0, int N) {
    int tid = blockIdx.x * 256 + threadIdx.x;
    if (tid >= N * 2) return;
    int n = tid >> 1;
    float d = dinv[n];
    float4 v = ((const float4*)x)[tid];
    v.x *= d; v.y *= d; v.z *= d; v.w *= d;
    ((float4*)t0)[tid] = v;
}

// ---- transforms. Core math in fp32; OB selects bf16 vs fp32 store. -------
// t = dinv*((dinv*acc [+ bprev])@W [+ pv])

template <int DIN, int DOUT, bool POSTB, bool OB>
__global__ __launch_bounds__(256) void transform_kernel(
    const float* __restrict__ accin, const float* __restrict__ W,
    const float* __restrict__ bias, const float* __restrict__ dinv,
    void* __restrict__ t, int wcols, int N) {
    __shared__ float Wl[DIN * DOUT];
    __shared__ float bl[(POSTB ? DOUT : DIN)];
    for (int i = threadIdx.x; i < DIN * DOUT; i += 256) {
        int k = i / DOUT, j = i - k * DOUT;
        Wl[i] = (j < wcols) ? W[k * wcols + j] : 0.0f;  // pad W5 cols to 4
    }
    for (int i = threadIdx.x; i < (POSTB ? DOUT : DIN); i += 256) bl[i] = bias[i];
    __syncthreads();

    int n = blockIdx.x * 256 + threadIdx.x;
    if (n >= N) return;
    float d = dinv[n];
    float h[DIN];
    const float4* a4 = (const float4*)accin + n * (DIN / 4);
#pragma unroll
    for (int k4 = 0; k4 < DIN / 4; k4++) {
        float4 v = a4[k4];
        if (POSTB) {
            h[4 * k4 + 0] = d * v.x; h[4 * k4 + 1] = d * v.y;
            h[4 * k4 + 2] = d * v.z; h[4 * k4 + 3] = d * v.w;
        } else {
            h[4 * k4 + 0] = d * v.x + bl[4 * k4 + 0];
            h[4 * k4 + 1] = d * v.y + bl[4 * k4 + 1];
            h[4 * k4 + 2] = d * v.z + bl[4 * k4 + 2];
            h[4 * k4 + 3] = d * v.w + bl[4 * k4 + 3];
        }
    }
    float4 o[DOUT / 4];
#pragma unroll
    for (int j = 0; j < DOUT / 4; j++)
        o[j] = POSTB ? make_float4(bl[4 * j], bl[4 * j + 1], bl[4 * j + 2], bl[4 * j + 3])
                     : make_float4(0.f, 0.f, 0.f, 0.f);
#pragma unroll
    for (int k = 0; k < DIN; k++) {
        float hk = h[k];
        const float4* w4 = (const float4*)&Wl[k * DOUT];
#pragma unroll
        for (int j = 0; j < DOUT / 4; j++) {
            float4 w = w4[j];
            o[j].x += hk * w.x; o[j].y += hk * w.y;
            o[j].z += hk * w.z; o[j].w += hk * w.w;
        }
    }
#pragma unroll
    for (int j = 0; j < DOUT / 4; j++) {
        o[j].x *= d; o[j].y *= d; o[j].z *= d; o[j].w *= d;
        if (OB) {
            ushort4 u = make_ushort4(f2bf(o[j].x), f2bf(o[j].y), f2bf(o[j].z), f2bf(o[j].w));
            ((ushort4*)t)[n * (DOUT / 4) + j] = u;
        } else {
            ((float4*)t)[n * (DOUT / 4) + j] = o[j];
        }
    }
}

// ---- CSR aggregation (fp32 t), unroll-4 ----------------------------------

template <int NC>
__global__ __launch_bounds__(256) void aggregate_csr(
    const int* __restrict__ start, const int* __restrict__ degi,
    const int* __restrict__ srow, const float* __restrict__ t,
    float* __restrict__ acc, int N) {
    int tid = blockIdx.x * 256 + threadIdx.x;
    int c = tid / NC, j = tid - (tid / NC) * NC;
    if (c >= N) return;
    int s = start[c];
    int d = degi[c];
    const float4* tv = (const float4*)t;
    float4 a0 = tv[c * NC + j];  // self-loop term
    float4 a1 = make_float4(0.f, 0.f, 0.f, 0.f);
    float4 a2 = make_float4(0.f, 0.f, 0.f, 0.f);
    float4 a3 = make_float4(0.f, 0.f, 0.f, 0.f);
    int i = 0;
    for (; i + 4 <= d; i += 4) {
        int r0 = srow[s + i + 0];
        int r1 = srow[s + i + 1];
        int r2 = srow[s + i + 2];
        int r3 = srow[s + i + 3];
        float4 v0 = tv[r0 * NC + j];
        float4 v1 = tv[r1 * NC + j];
        float4 v2 = tv[r2 * NC + j];
        float4 v3 = tv[r3 * NC + j];
        a0.x += v0.x; a0.y += v0.y; a0.z += v0.z; a0.w += v0.w;
        a1.x += v1.x; a1.y += v1.y; a1.z += v1.z; a1.w += v1.w;
        a2.x += v2.x; a2.y += v2.y; a2.z += v2.z; a2.w += v2.w;
        a3.x += v3.x; a3.y += v3.y; a3.z += v3.z; a3.w += v3.w;
    }
    for (; i < d; i++) {
        int r = srow[s + i];
        float4 v = tv[r * NC + j];
        a0.x += v.x; a0.y += v.y; a0.z += v.z; a0.w += v.w;
    }
    a0.x += a1.x + a2.x + a3.x;
    a0.y += a1.y + a2.y + a3.y;
    a0.z += a1.z + a2.z + a3.z;
    a0.w += a1.w + a2.w + a3.w;
    ((float4*)acc)[c * NC + j] = a0;
}

// ---- CSR aggregation from bf16 t (width 32), fp32 accumulate -------------
// 8 threads/node; each gathers ushort4 (8 B) → 64 B/row total (vs 128 fp32)

__global__ __launch_bounds__(256) void aggregate_csr_b(
    const int* __restrict__ start, const int* __restrict__ degi,
    const int* __restrict__ srow, const unsigned short* __restrict__ tb,
    float* __restrict__ acc, int N) {
    int tid = blockIdx.x * 256 + threadIdx.x;
    int c = tid >> 3, j = tid & 7;
    if (c >= N) return;
    int s = start[c];
    int d = degi[c];
    const ushort4* tv = (const ushort4*)tb;
    float4 a0 = bf2f4(tv[c * 8 + j]);  // self-loop term
    float4 a1 = make_float4(0.f, 0.f, 0.f, 0.f);
    float4 a2 = make_float4(0.f, 0.f, 0.f, 0.f);
    float4 a3 = make_float4(0.f, 0.f, 0.f, 0.f);
    int i = 0;
    for (; i + 4 <= d; i += 4) {
        int r0 = srow[s + i + 0];
        int r1 = srow[s + i + 1];
        int r2 = srow[s + i + 2];
        int r3 = srow[s + i + 3];
        float4 v0 = bf2f4(tv[r0 * 8 + j]);
        float4 v1 = bf2f4(tv[r1 * 8 + j]);
        float4 v2 = bf2f4(tv[r2 * 8 + j]);
        float4 v3 = bf2f4(tv[r3 * 8 + j]);
        a0.x += v0.x; a0.y += v0.y; a0.z += v0.z; a0.w += v0.w;
        a1.x += v1.x; a1.y += v1.y; a1.z += v1.z; a1.w += v1.w;
        a2.x += v2.x; a2.y += v2.y; a2.z += v2.z; a2.w += v2.w;
        a3.x += v3.x; a3.y += v3.y; a3.z += v3.z; a3.w += v3.w;
    }
    for (; i < d; i++) {
        int r = srow[s + i];
        float4 v = bf2f4(tv[r * 8 + j]);
        a0.x += v.x; a0.y += v.y; a0.z += v.z; a0.w += v.w;
    }
    a0.x += a1.x + a2.x + a3.x;
    a0.y += a1.y + a2.y + a3.y;
    a0.z += a1.z + a2.z + a3.z;
    a0.w += a1.w + a2.w + a3.w;
    ((float4*)acc)[c * 8 + j] = a0;
}

// ---- final: out fp32 [N,3] ------------------------------------------------

__global__ __launch_bounds__(256) void finalize_kernel(
    const float* __restrict__ acc4, const float* __restrict__ b5,
    const float* __restrict__ dinv, float* __restrict__ out, int N) {
    int i = blockIdx.x * 256 + threadIdx.x;
    if (i >= N * 3) return;
    int n = i / 3, j = i - n * 3;
    out[i] = dinv[n] * acc4[n * 4 + j] + b5[j];
}

// ---- launch --------------------------------------------------------------

extern "C" void kernel_launch(void* const* d_in, const int* in_sizes, int n_in,
                              void* d_out, int out_size, void* d_ws, size_t ws_size,
                              hipStream_t stream) {
    const float* x  = (const float*)d_in[0];
    const void*  ei = d_in[1];
    const float* W1 = (const float*)d_in[2];  const float* b1 = (const float*)d_in[3];
    const float* W2 = (const float*)d_in[4];  const float* b2 = (const float*)d_in[5];
    const float* W3 = (const float*)d_in[6];  const float* b3 = (const float*)d_in[7];
    const float* W4 = (const float*)d_in[8];  const float* b4 = (const float*)d_in[9];
    const float* W5 = (const float*)d_in[10]; const float* b5 = (const float*)d_in[11];
    float* out = (float*)d_out;

    char* p = (char*)d_ws;
    auto alloc = [&](size_t bytes) {
        char* r = p;
        p += (bytes + 255) & ~(size_t)255;
        return r;
    };
    int*   degi    = (int*)alloc(NN * 4);
    float* dinv    = (float*)alloc(NN * 4);
    int*   start   = (int*)alloc(NN * 4);
    int*   is64    = (int*)alloc(256);
    int*   bcount  = (int*)alloc(NB * 4);
    int*   bstart  = (int*)alloc((NB + 1) * 4);
    int*   bcursor = (int*)alloc(NB * 4);
    float* W12     = (float*)alloc(8 * 32 * 4);
    float* pv      = (float*)alloc(32 * 4);
    unsigned int*   epacked = (unsigned int*)alloc((size_t)NE * 4);
    int*            srow    = (int*)alloc((size_t)NE * 4);
    float*          A       = (float*)alloc((size_t)NN * 32 * 4);  // fp32 t (layer1) + scratch
    float*          B       = (float*)alloc((size_t)NN * 32 * 4);  // fp32 acc
    unsigned short* Tb      = (unsigned short*)alloc((size_t)NN * 32 * 2);  // bf16 t, layers 2-4
    float*          C       = (float*)alloc((size_t)NN * 4 * 4);   // t, layer 5 (3->4 pad)
    float*          D       = (float*)alloc((size_t)NN * 4 * 4);   // acc, layer 5
    if ((size_t)(p - (char*)d_ws) > ws_size) return;               // canary: zero output

    hipMemsetAsync(bcount, 0, NB * 4, stream);

    int gN = (NN + 255) / 256;
    detect_kernel<<<1, 256, 0, stream>>>((const unsigned int*)ei, is64);
    bucket_count_kernel<<<NBLK, 256, 0, stream>>>(ei, is64, bcount, NE);
    bucket_scan_kernel<<<1, 512, 0, stream>>>(bcount, bstart, bcursor, NE);
    bucket_scatter_kernel<<<NBLK, 256, 0, stream>>>(ei, is64, bcursor, epacked, NE);
    bucket_csr_kernel<<<NB, 256, 0, stream>>>(epacked, bstart, start, degi, dinv, srow, NN);
    prep_kernel<<<1, 256, 0, stream>>>(W1, W2, b1, W12, pv);

    int gAgg8 = (NN * 8 + 255) / 256;
    int gAgg2 = (NN * 2 + 255) / 256;

    // Layer 1 (reordered): aggregate width-8 x in fp32, fold W1@W2 later.
    scale8_kernel<<<gAgg2, 256, 0, stream>>>(x, dinv, A, NN);
    aggregate_csr<2><<<gAgg2, 256, 0, stream>>>(start, degi, srow, A, B, NN);

    // Layer 2: t2 = dinv*((dinv*acc0)@W12 + b1@W2), stored bf16
    transform_kernel<8, 32, true, true><<<gN, 256, 0, stream>>>(B, W12, pv, dinv, Tb, 32, NN);
    aggregate_csr_b<<<gAgg8, 256, 0, stream>>>(start, degi, srow, Tb, B, NN);

    // Layer 3 (bf16 t)
    transform_kernel<32, 32, false, true><<<gN, 256, 0, stream>>>(B, W3, b2, dinv, Tb, 32, NN);
    aggregate_csr_b<<<gAgg8, 256, 0, stream>>>(start, degi, srow, Tb, B, NN);

    // Layer 4 (bf16 t)
    transform_kernel<32, 32, false, true><<<gN, 256, 0, stream>>>(B, W4, b3, dinv, Tb, 32, NN);
    aggregate_csr_b<<<gAgg8, 256, 0, stream>>>(start, degi, srow, Tb, B, NN);

    // Layer 5 (fp32, padded dout 3->4 — output-adjacent, keep full precision)
    transform_kernel<32, 4, false, false><<<gN, 256, 0, stream>>>(B, W5, b4, dinv, C, 3, NN);
    aggregate_csr<1><<<gN, 256, 0, stream>>>(start, degi, srow, C, D, NN);

    finalize_kernel<<<(NN * 3 + 255) / 256, 256, 0, stream>>>(D, b5, dinv, out, NN);
}

// Round 9
// 205.229 us; speedup vs baseline: 2.5480x; 1.4110x over previous
//
#include <hip/hip_runtime.h>
#include <hip/hip_bf16.h>

#define NN 100000
#define NE 1600000
#define NB 391        // ceil(NN/256) buckets, bucket = col >> 8
#define EPB 4096      // edges per block in bucket passes
#define NBLK 391      // ceil(NE/EPB)

// ---- edge dtype detection (proven int32; kept as zero-cost guard) --------

__global__ __launch_bounds__(256) void detect_kernel(const unsigned int* __restrict__ w,
                                                     int* __restrict__ is64) {
    __shared__ int nz;
    if (threadIdx.x == 0) nz = 0;
    __syncthreads();
    if (w[2 * threadIdx.x + 1] != 0) atomicAdd(&nz, 1);
    __syncthreads();
    if (threadIdx.x == 0) *is64 = (nz == 0) ? 1 : 0;
}

static __device__ __forceinline__ int edge_at(const void* ei, int is64, long long pos) {
    return is64 ? (int)((const long long*)ei)[pos] : ((const int*)ei)[pos];
}

// ---- pass A: per-block LDS bucket histogram ------------------------------

__global__ __launch_bounds__(256) void bucket_count_kernel(const void* __restrict__ ei,
                                                           const int* __restrict__ is64,
                                                           int* __restrict__ bcount, int E) {
    __shared__ int lc[NB];
    int tid = threadIdx.x;
    for (int i = tid; i < NB; i += 256) lc[i] = 0;
    __syncthreads();
    int f = *is64;
    long long base = (long long)blockIdx.x * EPB;
    for (int k = 0; k < EPB / 256; k++) {
        long long e = base + k * 256 + tid;
        if (e < E) {
            int c = edge_at(ei, f, (long long)E + e);
            atomicAdd(&lc[c >> 8], 1);
        }
    }
    __syncthreads();
    for (int i = tid; i < NB; i += 256)
        if (lc[i]) atomicAdd(&bcount[i], lc[i]);
}

// ---- pass B: scan bucket counts (1 block) --------------------------------

__global__ __launch_bounds__(512) void bucket_scan_kernel(const int* __restrict__ bcount,
                                                          int* __restrict__ bstart,
                                                          int* __restrict__ bcursor, int E) {
    __shared__ int s[512];
    int tid = threadIdx.x;
    int v = (tid < NB) ? bcount[tid] : 0;
    int acc = v;
    s[tid] = v;
    __syncthreads();
    for (int off = 1; off < 512; off <<= 1) {
        int y = (tid >= off) ? s[tid - off] : 0;
        __syncthreads();
        acc += y;
        s[tid] = acc;
        __syncthreads();
    }
    if (tid < NB) {
        int excl = acc - v;
        bstart[tid] = excl;
        bcursor[tid] = excl;
    }
    if (tid == 0) bstart[NB] = E;
}

// ---- pass C: block-local bucket grouping + coalesced flush ---------------
// epacked[i] = (col&255)<<24 | row   (row < 2^24)

__global__ __launch_bounds__(256) void bucket_scatter_kernel(const void* __restrict__ ei,
                                                             const int* __restrict__ is64,
                                                             int* __restrict__ bcursor,
                                                             unsigned int* __restrict__ epacked,
                                                             int E) {
    __shared__ int lcount[NB];
    __shared__ int lstart[NB];
    __shared__ int lcur[NB];
    __shared__ int gbase[NB];
    __shared__ int ps[256];
    __shared__ unsigned int slotv[EPB];
    __shared__ unsigned short slotb[EPB];
    int tid = threadIdx.x;
    for (int i = tid; i < NB; i += 256) lcount[i] = 0;
    __syncthreads();
    int f = *is64;
    long long base = (long long)blockIdx.x * EPB;
    int r[EPB / 256], c[EPB / 256];
    for (int k = 0; k < EPB / 256; k++) {
        long long e = base + (long long)k * 256 + tid;
        if (e < E) {
            r[k] = edge_at(ei, f, e);
            c[k] = edge_at(ei, f, (long long)E + e);
            atomicAdd(&lcount[c[k] >> 8], 1);
        } else {
            r[k] = -1;
        }
    }
    __syncthreads();
    // pairwise exclusive scan of lcount (512-padded, 2 elems/thread)
    int e0 = (2 * tid < NB) ? lcount[2 * tid] : 0;
    int e1 = (2 * tid + 1 < NB) ? lcount[2 * tid + 1] : 0;
    int sum = e0 + e1, acc = sum;
    ps[tid] = sum;
    __syncthreads();
    for (int off = 1; off < 256; off <<= 1) {
        int y = (tid >= off) ? ps[tid - off] : 0;
        __syncthreads();
        acc += y;
        ps[tid] = acc;
        __syncthreads();
    }
    int excl = acc - sum;
    if (2 * tid < NB) lstart[2 * tid] = excl;
    if (2 * tid + 1 < NB) lstart[2 * tid + 1] = excl + e0;
    __syncthreads();
    for (int i = tid; i < NB; i += 256) lcur[i] = lstart[i];
    __syncthreads();
    // group edges by bucket in LDS
    for (int k = 0; k < EPB / 256; k++) {
        if (r[k] >= 0) {
            int b = c[k] >> 8;
            int pos = atomicAdd(&lcur[b], 1);
            slotv[pos] = ((unsigned)(c[k] & 255) << 24) | (unsigned)r[k];
            slotb[pos] = (unsigned short)b;
        }
    }
    __syncthreads();
    // reserve global slices, one atomic per touched bucket
    for (int i = tid; i < NB; i += 256) {
        int cnt = lcount[i];
        gbase[i] = cnt ? atomicAdd(&bcursor[i], cnt) : 0;
    }
    __syncthreads();
    // coalesced-ish flush (runs of same bucket are contiguous)
    long long rem = (long long)E - base;
    int total = (rem < EPB) ? (int)rem : EPB;
    for (int s2 = tid; s2 < total; s2 += 256) {
        int b = slotb[s2];
        int within = s2 - lstart[b];
        epacked[gbase[b] + within] = slotv[s2];
    }
}

// ---- pass D: per-bucket CSR build + start/deg/dinv (zero global atomics) --

__global__ __launch_bounds__(256) void bucket_csr_kernel(const unsigned int* __restrict__ epacked,
                                                         const int* __restrict__ bstart,
                                                         int* __restrict__ start,
                                                         int* __restrict__ degi,
                                                         float* __restrict__ dinv,
                                                         int* __restrict__ srow, int N) {
    __shared__ int lcount[256];
    __shared__ int lcur[256];
    __shared__ int ss[256];
    int b = blockIdx.x;
    int tid = threadIdx.x;
    int s0 = bstart[b];
    int cnt = bstart[b + 1] - s0;
    lcount[tid] = 0;
    __syncthreads();
    for (int i = tid; i < cnt; i += 256) {
        unsigned int v = epacked[s0 + i];
        atomicAdd(&lcount[v >> 24], 1);
    }
    __syncthreads();
    int myc = lcount[tid];
    int acc = myc;
    ss[tid] = myc;
    __syncthreads();
    for (int off = 1; off < 256; off <<= 1) {
        int y = (tid >= off) ? ss[tid - off] : 0;
        __syncthreads();
        acc += y;
        ss[tid] = acc;
        __syncthreads();
    }
    int excl = acc - myc;
    lcur[tid] = excl;
    int col = (b << 8) + tid;
    if (col < N) {
        start[col] = s0 + excl;
        degi[col] = myc;
        dinv[col] = 1.0f / sqrtf((float)myc + 1.0f);  // +1 self-loop
    }
    __syncthreads();
    for (int i = tid; i < cnt; i += 256) {
        unsigned int v = epacked[s0 + i];
        int p = atomicAdd(&lcur[v >> 24], 1);
        srow[s0 + p] = (int)(v & 0xFFFFFFu);  // row
    }
}

// ---- prep: fold weights. W45=W4@W5, W345=W3@W45, W2345=W2@W345,
//      Wt=W1@W2345 (8x3, padded to 8x4), c_k = (W_{k+1..5})^T b_k, c5=b5.

__global__ __launch_bounds__(256) void prep_kernel(
    const float* __restrict__ W1, const float* __restrict__ b1,
    const float* __restrict__ W2, const float* __restrict__ b2,
    const float* __restrict__ W3, const float* __restrict__ b3,
    const float* __restrict__ W4, const float* __restrict__ b4,
    const float* __restrict__ W5, const float* __restrict__ b5,
    float* __restrict__ Wt,      // [8*4]
    float* __restrict__ cv) {    // [5*4]
    __shared__ float w45[32 * 3], w345[32 * 3], w2345[32 * 3];
    int tid = threadIdx.x;
    int i = tid / 3, j = tid - 3 * (tid / 3);
    if (tid < 96) {
        float s = 0.0f;
        for (int k = 0; k < 32; k++) s += W4[i * 32 + k] * W5[k * 3 + j];
        w45[i * 3 + j] = s;
    }
    __syncthreads();
    if (tid < 96) {
        float s = 0.0f;
        for (int k = 0; k < 32; k++) s += W3[i * 32 + k] * w45[k * 3 + j];
        w345[i * 3 + j] = s;
    }
    __syncthreads();
    if (tid < 96) {
        float s = 0.0f;
        for (int k = 0; k < 32; k++) s += W2[i * 32 + k] * w345[k * 3 + j];
        w2345[i * 3 + j] = s;
    }
    __syncthreads();
    if (tid < 32) {
        int ii = tid >> 2, jj = tid & 3;  // 8 x 4
        float s = 0.0f;
        if (jj < 3)
            for (int k = 0; k < 32; k++) s += W1[ii * 32 + k] * w2345[k * 3 + jj];
        Wt[tid] = s;
    }
    if (tid >= 32 && tid < 52) {
        int kk = (tid - 32) >> 2, jj = (tid - 32) & 3;  // 5 x 4
        float s = 0.0f;
        if (jj < 3) {
            if (kk == 0) for (int k = 0; k < 32; k++) s += b1[k] * w2345[k * 3 + jj];
            if (kk == 1) for (int k = 0; k < 32; k++) s += b2[k] * w345[k * 3 + jj];
            if (kk == 2) for (int k = 0; k < 32; k++) s += b3[k] * w45[k * 3 + jj];
            if (kk == 3) for (int k = 0; k < 32; k++) s += b4[k] * W5[k * 3 + jj];
            if (kk == 4) s = b5[jj];
        }
        cv[tid - 32] = s;
    }
}

// ---- t0 = dinv ⊙ (X @ Wt)  (width 4, w-lane = 0) -------------------------

__global__ __launch_bounds__(256) void z_kernel(const float* __restrict__ x,
                                                const float* __restrict__ Wt,
                                                const float* __restrict__ dinv,
                                                float4* __restrict__ t0, int N) {
    __shared__ float4 Wl[8];
    if (threadIdx.x < 8) Wl[threadIdx.x] = ((const float4*)Wt)[threadIdx.x];
    __syncthreads();
    int n = blockIdx.x * 256 + threadIdx.x;
    if (n >= N) return;
    float d = dinv[n];
    const float4* x4 = (const float4*)x + n * 2;
    float4 a = x4[0], b = x4[1];
    float xs[8] = {a.x, a.y, a.z, a.w, b.x, b.y, b.z, b.w};
    float4 o = make_float4(0.f, 0.f, 0.f, 0.f);
#pragma unroll
    for (int k = 0; k < 8; k++) {
        float4 w = Wl[k];
        o.x += xs[k] * w.x; o.y += xs[k] * w.y; o.z += xs[k] * w.z;
    }
    o.x *= d; o.y *= d; o.z *= d; o.w = 0.0f;
    t0[n] = o;
}

// ---- propagation pass: a[c] = t[c] + Σ t[srow];  LAST: out = d*a + c5,
//      else: t' = d*(d*a + ck) = d*d*a + d*ck.   4 lanes per node. --------

template <bool LAST>
__global__ __launch_bounds__(256) void prop_kernel(
    const int* __restrict__ start, const int* __restrict__ degi,
    const int* __restrict__ srow, const float4* __restrict__ tin,
    const float* __restrict__ dinv, const float* __restrict__ cv, int k,
    float4* __restrict__ tout, float* __restrict__ out, int N) {
    int tid = blockIdx.x * 256 + threadIdx.x;
    int c = tid >> 2, q = tid & 3;
    if (c >= N) return;
    int s = start[c];
    int d = degi[c];
    float4 a = (q == 0) ? tin[c] : make_float4(0.f, 0.f, 0.f, 0.f);  // self-loop
    float4 a2 = make_float4(0.f, 0.f, 0.f, 0.f);
    int i = q;
    for (; i + 4 < d; i += 8) {
        int r0 = srow[s + i];
        int r1 = srow[s + i + 4];
        float4 v0 = tin[r0];
        float4 v1 = tin[r1];
        a.x += v0.x; a.y += v0.y; a.z += v0.z;
        a2.x += v1.x; a2.y += v1.y; a2.z += v1.z;
    }
    if (i < d) {
        float4 v = tin[srow[s + i]];
        a.x += v.x; a.y += v.y; a.z += v.z;
    }
    a.x += a2.x; a.y += a2.y; a.z += a2.z;
    // combine the 4 lanes of this node
    a.x += __shfl_xor(a.x, 1); a.y += __shfl_xor(a.y, 1); a.z += __shfl_xor(a.z, 1);
    a.x += __shfl_xor(a.x, 2); a.y += __shfl_xor(a.y, 2); a.z += __shfl_xor(a.z, 2);
    if (q == 0) {
        float dd = dinv[c];
        float cx = cv[k * 4 + 0], cy = cv[k * 4 + 1], cz = cv[k * 4 + 2];
        if (LAST) {
            out[c * 3 + 0] = dd * a.x + cx;
            out[c * 3 + 1] = dd * a.y + cy;
            out[c * 3 + 2] = dd * a.z + cz;
        } else {
            float d2 = dd * dd;
            float4 o;
            o.x = d2 * a.x + dd * cx;
            o.y = d2 * a.y + dd * cy;
            o.z = d2 * a.z + dd * cz;
            o.w = 0.0f;
            tout[c] = o;
        }
    }
}

// ---- launch --------------------------------------------------------------

extern "C" void kernel_launch(void* const* d_in, const int* in_sizes, int n_in,
                              void* d_out, int out_size, void* d_ws, size_t ws_size,
                              hipStream_t stream) {
    const float* x  = (const float*)d_in[0];
    const void*  ei = d_in[1];
    const float* W1 = (const float*)d_in[2];  const float* b1 = (const float*)d_in[3];
    const float* W2 = (const float*)d_in[4];  const float* b2 = (const float*)d_in[5];
    const float* W3 = (const float*)d_in[6];  const float* b3 = (const float*)d_in[7];
    const float* W4 = (const float*)d_in[8];  const float* b4 = (const float*)d_in[9];
    const float* W5 = (const float*)d_in[10]; const float* b5 = (const float*)d_in[11];
    float* out = (float*)d_out;

    char* p = (char*)d_ws;
    auto alloc = [&](size_t bytes) {
        char* r = p;
        p += (bytes + 255) & ~(size_t)255;
        return r;
    };
    int*   degi    = (int*)alloc(NN * 4);
    float* dinv    = (float*)alloc(NN * 4);
    int*   start   = (int*)alloc(NN * 4);
    int*   is64    = (int*)alloc(256);
    int*   bcount  = (int*)alloc(NB * 4);
    int*   bstart  = (int*)alloc((NB + 1) * 4);
    int*   bcursor = (int*)alloc(NB * 4);
    float* Wt      = (float*)alloc(8 * 4 * 4);
    float* cv      = (float*)alloc(5 * 4 * 4);
    unsigned int* epacked = (unsigned int*)alloc((size_t)NE * 4);
    int*          srow    = (int*)alloc((size_t)NE * 4);
    float4*       Ta      = (float4*)alloc((size_t)NN * 16);
    float4*       Tb      = (float4*)alloc((size_t)NN * 16);
    if ((size_t)(p - (char*)d_ws) > ws_size) return;  // canary: zero output

    hipMemsetAsync(bcount, 0, NB * 4, stream);

    int gN = (NN + 255) / 256;
    int gP = (NN * 4 + 255) / 256;
    detect_kernel<<<1, 256, 0, stream>>>((const unsigned int*)ei, is64);
    bucket_count_kernel<<<NBLK, 256, 0, stream>>>(ei, is64, bcount, NE);
    bucket_scan_kernel<<<1, 512, 0, stream>>>(bcount, bstart, bcursor, NE);
    bucket_scatter_kernel<<<NBLK, 256, 0, stream>>>(ei, is64, bcursor, epacked, NE);
    bucket_csr_kernel<<<NB, 256, 0, stream>>>(epacked, bstart, start, degi, dinv, srow, NN);
    prep_kernel<<<1, 256, 0, stream>>>(W1, b1, W2, b2, W3, b3, W4, b4, W5, b5, Wt, cv);

    // g_k = Â g_{k-1} + 1 c_k^T in folded t = dinv ⊙ g coordinates
    z_kernel<<<gN, 256, 0, stream>>>(x, Wt, dinv, Ta, NN);
    prop_kernel<false><<<gP, 256, 0, stream>>>(start, degi, srow, Ta, dinv, cv, 0, Tb, nullptr, NN);
    prop_kernel<false><<<gP, 256, 0, stream>>>(start, degi, srow, Tb, dinv, cv, 1, Ta, nullptr, NN);
    prop_kernel<false><<<gP, 256, 0, stream>>>(start, degi, srow, Ta, dinv, cv, 2, Tb, nullptr, NN);
    prop_kernel<false><<<gP, 256, 0, stream>>>(start, degi, srow, Tb, dinv, cv, 3, Ta, nullptr, NN);
    prop_kernel<true><<<gP, 256, 0, stream>>>(start, degi, srow, Ta, dinv, cv, 4, nullptr, out, NN);
}